// Round 1
// 780.562 us; speedup vs baseline: 1.0538x; 1.0538x over previous
//
#include <hip/hip_runtime.h>
#include <cstdint>
#include <cstddef>

typedef __attribute__((ext_vector_type(8))) short short8;
typedef __attribute__((ext_vector_type(4))) float f32x4;

#define SCALE 0.17677669529663687f
#define KOFF 25165824UL
#define VOFF 50331648UL

__device__ __forceinline__ float bf2f(unsigned short u){
  union { unsigned int i; float f; } x; x.i = ((unsigned int)u) << 16; return x.f;
}
__device__ __forceinline__ unsigned short f2bf(float f){
  union { float f; unsigned int i; } x; x.f = f;
  unsigned int u = x.i;
  unsigned int r = u + 0x7fffu + ((u >> 16) & 1u);
  return (unsigned short)(r >> 16);
}

// Detect whether external float tensors are stored as bf16 (1) or fp32 (0).
__device__ __forceinline__ int detect_bf16(const void* probe){
  const unsigned short* p = (const unsigned short*)probe;
  int ok = 1;
  #pragma unroll
  for (int i = 0; i < 32; i++){
    unsigned short u = p[2*i];
    int e = (u >> 7) & 0xFF;
    ok &= (e >= 0x60 && e <= 0x90) ? 1 : 0;
  }
  return ok;
}

__device__ __forceinline__ float ld1(const void* p, size_t i, int isbf){
  return isbf ? bf2f(((const unsigned short*)p)[i]) : ((const float*)p)[i];
}
// 8 consecutive elements (i % 8 == 0) -> bf16 frag (RTE conversion on fp32 path)
__device__ __forceinline__ short8 ld8(const void* p, size_t i, int isbf){
  short8 r;
  if (isbf){
    r = *(const short8*)((const unsigned short*)p + i);
  } else {
    const float4* f = (const float4*)((const float*)p + i);
    float4 u0 = f[0], u1 = f[1];
    r[0] = (short)f2bf(u0.x); r[1] = (short)f2bf(u0.y);
    r[2] = (short)f2bf(u0.z); r[3] = (short)f2bf(u0.w);
    r[4] = (short)f2bf(u1.x); r[5] = (short)f2bf(u1.y);
    r[6] = (short)f2bf(u1.z); r[7] = (short)f2bf(u1.w);
  }
  return r;
}
// 4 consecutive elements (i % 4 == 0) -> float4
__device__ __forceinline__ float4 ld4(const void* p, size_t i, int isbf){
  if (!isbf) return *(const float4*)((const float*)p + i);
  const unsigned short* u = (const unsigned short*)p + i;
  uint2 w = *(const uint2*)u;
  float4 r;
  r.x = bf2f((unsigned short)(w.x & 0xffffu)); r.y = bf2f((unsigned short)(w.x >> 16));
  r.z = bf2f((unsigned short)(w.y & 0xffffu)); r.w = bf2f((unsigned short)(w.y >> 16));
  return r;
}

// ---------------- DynamicPosBias MLP: [465,2] -> [465,6] (fp32 out) ----------------
__global__ void posmlp_kernel(const void* __restrict__ probe,
    const void* __restrict__ rpe,
    const void* __restrict__ w0, const void* __restrict__ b0,
    const void* __restrict__ g1, const void* __restrict__ be1,
    const void* __restrict__ w1, const void* __restrict__ bb1,
    const void* __restrict__ g2, const void* __restrict__ be2,
    const void* __restrict__ w2, const void* __restrict__ bb2,
    const void* __restrict__ g3, const void* __restrict__ be3,
    const void* __restrict__ w3, const void* __restrict__ bb3,
    float* __restrict__ pos_table)
{
  const int isbf = detect_bf16(probe);
  int r = blockIdx.x * blockDim.x + threadIdx.x;
  if (r >= 465) return;
  float x0 = ld1(rpe, 2*r, isbf), x1 = ld1(rpe, 2*r+1, isbf);
  float h[12], y[12];
  #pragma unroll
  for (int j=0;j<12;j++) h[j] = x0*ld1(w0,j,isbf) + x1*ld1(w0,12+j,isbf) + ld1(b0,j,isbf);

  {
    float m=0.f;
    #pragma unroll
    for (int j=0;j<12;j++) m += h[j];
    m *= (1.f/12.f);
    float v=0.f;
    #pragma unroll
    for (int j=0;j<12;j++){ float d=h[j]-m; v += d*d; }
    v *= (1.f/12.f);
    float rs = 1.0f/sqrtf(v + 1e-5f);
    #pragma unroll
    for (int j=0;j<12;j++) y[j] = fmaxf((h[j]-m)*rs*ld1(g1,j,isbf) + ld1(be1,j,isbf), 0.f);
    #pragma unroll
    for (int j=0;j<12;j++){
      float s = ld1(bb1,j,isbf);
      #pragma unroll
      for (int i=0;i<12;i++) s += y[i]*ld1(w1,i*12+j,isbf);
      h[j] = s;
    }
  }
  {
    float m=0.f;
    #pragma unroll
    for (int j=0;j<12;j++) m += h[j];
    m *= (1.f/12.f);
    float v=0.f;
    #pragma unroll
    for (int j=0;j<12;j++){ float d=h[j]-m; v += d*d; }
    v *= (1.f/12.f);
    float rs = 1.0f/sqrtf(v + 1e-5f);
    #pragma unroll
    for (int j=0;j<12;j++) y[j] = fmaxf((h[j]-m)*rs*ld1(g2,j,isbf) + ld1(be2,j,isbf), 0.f);
    #pragma unroll
    for (int j=0;j<12;j++){
      float s = ld1(bb2,j,isbf);
      #pragma unroll
      for (int i=0;i<12;i++) s += y[i]*ld1(w2,i*12+j,isbf);
      h[j] = s;
    }
  }
  {
    float m=0.f;
    #pragma unroll
    for (int j=0;j<12;j++) m += h[j];
    m *= (1.f/12.f);
    float v=0.f;
    #pragma unroll
    for (int j=0;j<12;j++){ float d=h[j]-m; v += d*d; }
    v *= (1.f/12.f);
    float rs = 1.0f/sqrtf(v + 1e-5f);
    #pragma unroll
    for (int j=0;j<12;j++) y[j] = fmaxf((h[j]-m)*rs*ld1(g3,j,isbf) + ld1(be3,j,isbf), 0.f);
    #pragma unroll
    for (int o=0;o<6;o++){
      float s = ld1(bb3,o,isbf);
      #pragma unroll
      for (int i=0;i<12;i++) s += y[i]*ld1(w3,i*6+o,isbf);
      pos_table[r*6+o] = s;
    }
  }
}

// ---------------- gather (native order): rpbN[h][m][n] = pos[rel[m][n]][h], bf16 ----------------
__global__ void gatherN_kernel(const int* __restrict__ rel_idx,
                               const float* __restrict__ pos_table,
                               unsigned short* __restrict__ rpbN)
{
  const int idx = blockIdx.x * 256 + threadIdx.x;   // 0..16383 over m*128+n
  const int h = blockIdx.y;
  rpbN[h*16384 + idx] = f2bf(pos_table[rel_idx[idx]*6 + h]);
}

// ---------------- pooled query: avg (c<96) / max (c>=96), *scale, bf16 out ----------------
__global__ void pool_kernel(const void* __restrict__ qkv,
                            unsigned short* __restrict__ poolq)
{
  const int isbf = detect_bf16(qkv);
  const int b = blockIdx.y;
  const int n = blockIdx.x;            // n = ph*16 + pw
  const int t = threadIdx.x;           // 0..191
  const int cg = t % 48, sub = t / 48; // 48 float4 channel groups, 4 token subsets
  const int ph = n >> 4, pw = n & 15;
  const size_t cell = ((size_t)(b*16384 + ph*16*128 + pw*8))*192 + cg*4;
  const bool avg = (cg < 24);
  float4 acc;
  if (avg){ acc.x=0.f; acc.y=0.f; acc.z=0.f; acc.w=0.f; }
  else    { acc.x=-3.4e38f; acc.y=-3.4e38f; acc.z=-3.4e38f; acc.w=-3.4e38f; }
  #pragma unroll
  for (int hh=0; hh<4; hh++){
    const int hi = sub*4 + hh;
    #pragma unroll
    for (int wi=0; wi<8; wi++){
      float4 xv = ld4(qkv, cell + (size_t)(hi*128 + wi)*192, isbf);
      if (avg){ acc.x+=xv.x; acc.y+=xv.y; acc.z+=xv.z; acc.w+=xv.w; }
      else { acc.x=fmaxf(acc.x,xv.x); acc.y=fmaxf(acc.y,xv.y);
             acc.z=fmaxf(acc.z,xv.z); acc.w=fmaxf(acc.w,xv.w); }
    }
  }
  __shared__ float4 pr[4][48];
  pr[sub][cg] = acc;
  __syncthreads();
  if (sub == 0){
    #pragma unroll
    for (int s=1; s<4; s++){
      float4 xv = pr[s][cg];
      if (avg){ acc.x+=xv.x; acc.y+=xv.y; acc.z+=xv.z; acc.w+=xv.w; }
      else { acc.x=fmaxf(acc.x,xv.x); acc.y=fmaxf(acc.y,xv.y);
             acc.z=fmaxf(acc.z,xv.z); acc.w=fmaxf(acc.w,xv.w); }
    }
    if (avg){ acc.x*=(1.f/128.f); acc.y*=(1.f/128.f); acc.z*=(1.f/128.f); acc.w*=(1.f/128.f); }
    unsigned int lo = (unsigned int)f2bf(acc.x*SCALE) | ((unsigned int)f2bf(acc.y*SCALE) << 16);
    unsigned int hi = (unsigned int)f2bf(acc.z*SCALE) | ((unsigned int)f2bf(acc.w*SCALE) << 16);
    uint2 st; st.x = lo; st.y = hi;
    *(uint2*)(poolq + ((size_t)b*128 + n)*192 + cg*4) = st;
  }
}

// ---------------- attention: one block per (window, batch, head) ----------------
// New decomposition: wave wv owns 32 QUERIES (m in [wv*32, wv*32+32)) and all 128 tokens.
//  - softmax fully wave-local (in-lane + shfl_xor over quads), single pass
//  - P->PV handoff in-register via k-permutation pi(k) = ((k>>2)&1)*16 + (k>>3)*4 + (k&3):
//    PV B-frag for chunk jt = lane's own acc[2jt],acc[2jt+1] packed to bf16; V staged with
//    matching permuted column s(tok) so the A-frag is a contiguous short8 read.
//  - bias (mask+rpb) added as scalar fp32 (no identity-MFMA, no bf16 rounding of mask)
//  - O^T stored directly as float4 (d rows contiguous per lane) -> no LDS epilogue
// One barrier total (post-stage). LDS = 10240 (Kt) + 8704 (Vt) = 18944 B.
__global__ __launch_bounds__(256, 4)
void attn_kernel(const void* __restrict__ qkv,
                 const unsigned short* __restrict__ poolq,
                 const void* __restrict__ mask,
                 const unsigned short* __restrict__ rpbN,
                 void* __restrict__ out)
{
  const int isbf = detect_bf16(qkv);
  const int iw = blockIdx.x, b = blockIdx.y, head = blockIdx.z;
  const int hb = iw >> 3, wb = iw & 7;   // window: h in [hb*8,+8), w in [wb*16,+16)
  const int qb = iw & 7;                 // torch .repeat quirk: pooled-q batch = iw % 8
  const int tid = threadIdx.x;
  const int lane = tid & 63, wv = tid >> 6;
  const int quad = lane >> 4, c16 = lane & 15;

  __shared__ unsigned short Kt[128][40];   // K row-major, pitch 40 (10240 B)
  __shared__ unsigned short Vt[32][136];   // V^T with permuted columns (8704 B)

  // ---- stage Kt and Vt (cooperative; each thread one half-row of one token) ----
  {
    const int tok = tid >> 1;            // token 0..127
    const int dh  = (tid & 1) << 4;      // dim half 0 / 16
    const size_t rowidx = ((size_t)((b*128 + hb*8 + (tok>>4))*128 + wb*16 + (tok&15)))*192 + head*32 + dh;
    short8 k0 = ld8(qkv, KOFF + rowidx, isbf);
    short8 k1 = ld8(qkv, KOFF + rowidx + 8, isbf);
    *(short8*)(&Kt[tok][dh])     = k0;
    *(short8*)(&Kt[tok][dh + 8]) = k1;
    short8 v0 = ld8(qkv, VOFF + rowidx, isbf);
    short8 v1 = ld8(qkv, VOFF + rowidx + 8, isbf);
    // permuted column: within each 32-token block, n = b16*16+q*4+r -> pos = q*8+b16*4+r
    const int t5 = tok & 31;
    const int stok = (tok & ~31) | (((t5>>2)&3)*8) | (((t5>>4)&1)*4) | (t5&3);
    #pragma unroll
    for (int u=0; u<8; u++){
      Vt[dh + u][stok]     = (unsigned short)v0[u];
      Vt[dh + 8 + u][stok] = (unsigned short)v1[u];
    }
  }

  // ---- Q frags for this wave's 32 queries (poolq is small + L2-hot) ----
  short8 qf[2];
  #pragma unroll
  for (int tm=0; tm<2; tm++)
    qf[tm] = *(const short8*)(poolq + ((size_t)(qb*128 + (wv*2+tm)*16 + c16))*192 + head*32 + quad*8);

  __syncthreads();   // ONLY barrier: Kt/Vt visible to all waves

  // ---- S^T tiles: D[i = token n (quad*4+r within tile tn)][j = query m (c16)] ----
  // acc[tn][tm]; m = wv*32 + tm*16 + c16; n = tn*16 + quad*4 + r
  f32x4 acc[8][2];
  const size_t mbase = (size_t)iw*16384;
  const size_t rbase = (size_t)head*16384;
  #pragma unroll
  for (int tn=0; tn<8; tn++){
    short8 kA = *(const short8*)(&Kt[tn*16 + c16][quad*8]);
    f32x4 z = {0.f, 0.f, 0.f, 0.f};
    acc[tn][0] = __builtin_amdgcn_mfma_f32_16x16x32_bf16(kA, qf[0], z, 0, 0, 0);
    acc[tn][1] = __builtin_amdgcn_mfma_f32_16x16x32_bf16(kA, qf[1], z, 0, 0, 0);
    // scalar fp32 bias add: mask[iw][m][n] + rpb[head][m][n]
    const int nb = tn*16 + quad*4;
    #pragma unroll
    for (int tm=0; tm<2; tm++){
      const int m = wv*32 + tm*16 + c16;
      float4 mv = ld4(mask, mbase + (size_t)m*128 + nb, isbf);
      uint2 rv = *(const uint2*)(rpbN + rbase + (size_t)m*128 + nb);
      acc[tn][tm][0] += mv.x + bf2f((unsigned short)(rv.x & 0xffffu));
      acc[tn][tm][1] += mv.y + bf2f((unsigned short)(rv.x >> 16));
      acc[tn][tm][2] += mv.z + bf2f((unsigned short)(rv.y & 0xffffu));
      acc[tn][tm][3] += mv.w + bf2f((unsigned short)(rv.y >> 16));
    }
  }

  // ---- wave-local softmax over tokens per query + in-register bf16 pack ----
  float wsc[2];
  short8 pa[4][2];
  #pragma unroll
  for (int tm=0; tm<2; tm++){
    float mx = acc[0][tm][0];
    #pragma unroll
    for (int tn=0; tn<8; tn++)
      #pragma unroll
      for (int r=0; r<4; r++) mx = fmaxf(mx, acc[tn][tm][r]);
    mx = fmaxf(mx, __shfl_xor(mx, 16));
    mx = fmaxf(mx, __shfl_xor(mx, 32));
    float s = 0.f;
    #pragma unroll
    for (int tn=0; tn<8; tn++)
      #pragma unroll
      for (int r=0; r<4; r++){
        float p = __expf(acc[tn][tm][r] - mx);
        acc[tn][tm][r] = p;
        s += p;
      }
    s += __shfl_xor(s, 16);
    s += __shfl_xor(s, 32);
    wsc[tm] = 1.0f / s;   // applied to O at the end (P stays unnormalized in [0,1])
    // pack PV B-frags: pa[jt][tm][u] = P[jt*32 + pi(quad*8+u)][m]  (all in-lane)
    #pragma unroll
    for (int jt=0; jt<4; jt++)
      #pragma unroll
      for (int u=0; u<8; u++)
        pa[jt][tm][u] = (short)(__float_as_uint(acc[2*jt + (u>>2)][tm][u & 3]) >> 16);
  }

  // ---- O^T = V^T · P : D[i = d][j = m], k-order permuted consistently via Vt columns ----
  f32x4 o[2][2];   // o[tm][dt]
  #pragma unroll
  for (int tm=0; tm<2; tm++)
    #pragma unroll
    for (int dt=0; dt<2; dt++){ f32x4 z = {0.f,0.f,0.f,0.f}; o[tm][dt] = z; }
  #pragma unroll
  for (int jt=0; jt<4; jt++){
    short8 vA0 = *(const short8*)&Vt[c16][jt*32 + quad*8];
    short8 vA1 = *(const short8*)&Vt[16 + c16][jt*32 + quad*8];
    o[0][0] = __builtin_amdgcn_mfma_f32_16x16x32_bf16(vA0, pa[jt][0], o[0][0], 0, 0, 0);
    o[0][1] = __builtin_amdgcn_mfma_f32_16x16x32_bf16(vA1, pa[jt][0], o[0][1], 0, 0, 0);
    o[1][0] = __builtin_amdgcn_mfma_f32_16x16x32_bf16(vA0, pa[jt][1], o[1][0], 0, 0, 0);
    o[1][1] = __builtin_amdgcn_mfma_f32_16x16x32_bf16(vA1, pa[jt][1], o[1][1], 0, 0, 0);
  }

  // ---- epilogue: scale by 1/S and store directly (d = dt*16 + quad*4 + r contiguous) ----
  #pragma unroll
  for (int tm=0; tm<2; tm++){
    const int m = wv*32 + tm*16 + c16;
    const int hh = hb*8 + (m >> 4), ww = wb*16 + (m & 15);
    const size_t obase = ((size_t)((b*128 + hh)*128 + ww))*192 + head*32;
    #pragma unroll
    for (int dt=0; dt<2; dt++){
      float4 val;
      val.x = o[tm][dt][0] * wsc[tm];
      val.y = o[tm][dt][1] * wsc[tm];
      val.z = o[tm][dt][2] * wsc[tm];
      val.w = o[tm][dt][3] * wsc[tm];
      const size_t off = obase + dt*16 + quad*4;
      if (isbf){
        unsigned int lo = (unsigned int)f2bf(val.x) | ((unsigned int)f2bf(val.y) << 16);
        unsigned int hi = (unsigned int)f2bf(val.z) | ((unsigned int)f2bf(val.w) << 16);
        uint2 st; st.x = lo; st.y = hi;
        *(uint2*)((unsigned short*)out + off) = st;
      } else {
        *(float4*)((float*)out + off) = val;
      }
    }
  }
}

extern "C" void kernel_launch(void* const* d_in, const int* in_sizes, int n_in,
                              void* d_out, int out_size, void* d_ws, size_t ws_size,
                              hipStream_t stream)
{
  const void* qkv  = d_in[0];
  const void* mask = d_in[1];
  const int* rel_idx = (const int*)d_in[17];

  float* pos_table     = (float*)d_ws;                                   // 11160 B
  unsigned short* rpbN = (unsigned short*)((char*)d_ws + 12288);         // 6*16384*2 = 196608 B
  unsigned short* poolq= (unsigned short*)((char*)d_ws + 12288 + 196608);// 8*128*192*2 = 196608 B

  posmlp_kernel<<<1, 512, 0, stream>>>(qkv, d_in[16],
      d_in[2], d_in[3], d_in[4], d_in[5], d_in[6], d_in[7],
      d_in[8], d_in[9], d_in[10], d_in[11], d_in[12], d_in[13],
      d_in[14], d_in[15], pos_table);
  gatherN_kernel<<<dim3(64, 6), 256, 0, stream>>>(rel_idx, pos_table, rpbN);
  pool_kernel<<<dim3(128, 8), 192, 0, stream>>>(qkv, poolq);
  attn_kernel<<<dim3(128, 8, 6), 256, 0, stream>>>(qkv, poolq, mask, rpbN, d_out);
}

// Round 4
// 776.114 us; speedup vs baseline: 1.0599x; 1.0057x over previous
//
#include <hip/hip_runtime.h>
#include <cstdint>
#include <cstddef>

typedef __attribute__((ext_vector_type(8))) short short8;
typedef __attribute__((ext_vector_type(4))) float f32x4;

#define SCALE 0.17677669529663687f
#define KOFF 25165824UL
#define VOFF 50331648UL

__device__ __forceinline__ float bf2f(unsigned short u){
  union { unsigned int i; float f; } x; x.i = ((unsigned int)u) << 16; return x.f;
}
__device__ __forceinline__ unsigned short f2bf(float f){
  union { float f; unsigned int i; } x; x.f = f;
  unsigned int u = x.i;
  unsigned int r = u + 0x7fffu + ((u >> 16) & 1u);
  return (unsigned short)(r >> 16);
}

// Detect whether external float tensors are stored as bf16 (1) or fp32 (0).
__device__ __forceinline__ int detect_bf16(const void* probe){
  const unsigned short* p = (const unsigned short*)probe;
  int ok = 1;
  #pragma unroll
  for (int i = 0; i < 32; i++){
    unsigned short u = p[2*i];
    int e = (u >> 7) & 0xFF;
    ok &= (e >= 0x60 && e <= 0x90) ? 1 : 0;
  }
  return ok;
}

__device__ __forceinline__ float ld1(const void* p, size_t i, int isbf){
  return isbf ? bf2f(((const unsigned short*)p)[i]) : ((const float*)p)[i];
}
// 8 consecutive elements (i % 8 == 0) -> bf16 frag (RTE conversion on fp32 path)
__device__ __forceinline__ short8 ld8(const void* p, size_t i, int isbf){
  short8 r;
  if (isbf){
    r = *(const short8*)((const unsigned short*)p + i);
  } else {
    const float4* f = (const float4*)((const float*)p + i);
    float4 u0 = f[0], u1 = f[1];
    r[0] = (short)f2bf(u0.x); r[1] = (short)f2bf(u0.y);
    r[2] = (short)f2bf(u0.z); r[3] = (short)f2bf(u0.w);
    r[4] = (short)f2bf(u1.x); r[5] = (short)f2bf(u1.y);
    r[6] = (short)f2bf(u1.z); r[7] = (short)f2bf(u1.w);
  }
  return r;
}
// 4 consecutive elements (i % 4 == 0) -> float4
__device__ __forceinline__ float4 ld4(const void* p, size_t i, int isbf){
  if (!isbf) return *(const float4*)((const float*)p + i);
  const unsigned short* u = (const unsigned short*)p + i;
  uint2 w = *(const uint2*)u;
  float4 r;
  r.x = bf2f((unsigned short)(w.x & 0xffffu)); r.y = bf2f((unsigned short)(w.x >> 16));
  r.z = bf2f((unsigned short)(w.y & 0xffffu)); r.w = bf2f((unsigned short)(w.y >> 16));
  return r;
}

// ---------------- DynamicPosBias MLP: [465,2] -> [465,6] (fp32 out) ----------------
__global__ void posmlp_kernel(const void* __restrict__ probe,
    const void* __restrict__ rpe,
    const void* __restrict__ w0, const void* __restrict__ b0,
    const void* __restrict__ g1, const void* __restrict__ be1,
    const void* __restrict__ w1, const void* __restrict__ bb1,
    const void* __restrict__ g2, const void* __restrict__ be2,
    const void* __restrict__ w2, const void* __restrict__ bb2,
    const void* __restrict__ g3, const void* __restrict__ be3,
    const void* __restrict__ w3, const void* __restrict__ bb3,
    float* __restrict__ pos_table)
{
  const int isbf = detect_bf16(probe);
  int r = blockIdx.x * blockDim.x + threadIdx.x;
  if (r >= 465) return;
  float x0 = ld1(rpe, 2*r, isbf), x1 = ld1(rpe, 2*r+1, isbf);
  float h[12], y[12];
  #pragma unroll
  for (int j=0;j<12;j++) h[j] = x0*ld1(w0,j,isbf) + x1*ld1(w0,12+j,isbf) + ld1(b0,j,isbf);

  {
    float m=0.f;
    #pragma unroll
    for (int j=0;j<12;j++) m += h[j];
    m *= (1.f/12.f);
    float v=0.f;
    #pragma unroll
    for (int j=0;j<12;j++){ float d=h[j]-m; v += d*d; }
    v *= (1.f/12.f);
    float rs = 1.0f/sqrtf(v + 1e-5f);
    #pragma unroll
    for (int j=0;j<12;j++) y[j] = fmaxf((h[j]-m)*rs*ld1(g1,j,isbf) + ld1(be1,j,isbf), 0.f);
    #pragma unroll
    for (int j=0;j<12;j++){
      float s = ld1(bb1,j,isbf);
      #pragma unroll
      for (int i=0;i<12;i++) s += y[i]*ld1(w1,i*12+j,isbf);
      h[j] = s;
    }
  }
  {
    float m=0.f;
    #pragma unroll
    for (int j=0;j<12;j++) m += h[j];
    m *= (1.f/12.f);
    float v=0.f;
    #pragma unroll
    for (int j=0;j<12;j++){ float d=h[j]-m; v += d*d; }
    v *= (1.f/12.f);
    float rs = 1.0f/sqrtf(v + 1e-5f);
    #pragma unroll
    for (int j=0;j<12;j++) y[j] = fmaxf((h[j]-m)*rs*ld1(g2,j,isbf) + ld1(be2,j,isbf), 0.f);
    #pragma unroll
    for (int j=0;j<12;j++){
      float s = ld1(bb2,j,isbf);
      #pragma unroll
      for (int i=0;i<12;i++) s += y[i]*ld1(w2,i*12+j,isbf);
      h[j] = s;
    }
  }
  {
    float m=0.f;
    #pragma unroll
    for (int j=0;j<12;j++) m += h[j];
    m *= (1.f/12.f);
    float v=0.f;
    #pragma unroll
    for (int j=0;j<12;j++){ float d=h[j]-m; v += d*d; }
    v *= (1.f/12.f);
    float rs = 1.0f/sqrtf(v + 1e-5f);
    #pragma unroll
    for (int j=0;j<12;j++) y[j] = fmaxf((h[j]-m)*rs*ld1(g3,j,isbf) + ld1(be3,j,isbf), 0.f);
    #pragma unroll
    for (int o=0;o<6;o++){
      float s = ld1(bb3,o,isbf);
      #pragma unroll
      for (int i=0;i<12;i++) s += y[i]*ld1(w3,i*6+o,isbf);
      pos_table[r*6+o] = s;
    }
  }
}

// ---------------- permuted rpb gather: rpbP[h][tn][wv][lane][tm][r] (bf16) ----------------
// value = f2bf(pos_table[rel_idx[m*128+n]*6 + h])  (same rounding as round-1 gatherN)
//   m = wv*32 + tm*16 + (lane&15), n = tn*16 + (lane>>4)*4 + r
// attn's lane then reads ONE uint4 per tn: {tm0 r0..3, tm1 r0..3}, fully coalesced.
__global__ void gatherP_kernel(const int* __restrict__ rel_idx,
                               const float* __restrict__ pos_table,
                               unsigned short* __restrict__ rpbP)
{
  const int t = blockIdx.x * 256 + threadIdx.x;   // 24576 total
  const int tm = t & 1, lane = (t >> 1) & 63, wv = (t >> 7) & 3, tn = (t >> 9) & 7, h = t >> 12;
  const int c16 = lane & 15, quad = lane >> 4;
  const int m = wv*32 + tm*16 + c16;
  const int nb = tn*16 + quad*4;
  const int* ri = rel_idx + m*128 + nb;
  unsigned int lo = (unsigned int)f2bf(pos_table[ri[0]*6 + h])
                  | ((unsigned int)f2bf(pos_table[ri[1]*6 + h]) << 16);
  unsigned int hi = (unsigned int)f2bf(pos_table[ri[2]*6 + h])
                  | ((unsigned int)f2bf(pos_table[ri[3]*6 + h]) << 16);
  uint2 st; st.x = lo; st.y = hi;
  *(uint2*)(rpbP + ((size_t)((h*8 + tn)*4 + wv)*64 + lane)*8 + tm*4) = st;
}

// ---------------- pooled query: avg (c<96) / max (c>=96), *scale, bf16 out ----------------
__global__ void pool_kernel(const void* __restrict__ qkv,
                            unsigned short* __restrict__ poolq)
{
  const int isbf = detect_bf16(qkv);
  const int b = blockIdx.y;
  const int n = blockIdx.x;            // n = ph*16 + pw
  const int t = threadIdx.x;           // 0..191
  const int cg = t % 48, sub = t / 48; // 48 float4 channel groups, 4 token subsets
  const int ph = n >> 4, pw = n & 15;
  const size_t cell = ((size_t)(b*16384 + ph*16*128 + pw*8))*192 + cg*4;
  const bool avg = (cg < 24);
  float4 acc;
  if (avg){ acc.x=0.f; acc.y=0.f; acc.z=0.f; acc.w=0.f; }
  else    { acc.x=-3.4e38f; acc.y=-3.4e38f; acc.z=-3.4e38f; acc.w=-3.4e38f; }
  #pragma unroll
  for (int hh=0; hh<4; hh++){
    const int hi = sub*4 + hh;
    #pragma unroll
    for (int wi=0; wi<8; wi++){
      float4 xv = ld4(qkv, cell + (size_t)(hi*128 + wi)*192, isbf);
      if (avg){ acc.x+=xv.x; acc.y+=xv.y; acc.z+=xv.z; acc.w+=xv.w; }
      else { acc.x=fmaxf(acc.x,xv.x); acc.y=fmaxf(acc.y,xv.y);
             acc.z=fmaxf(acc.z,xv.z); acc.w=fmaxf(acc.w,xv.w); }
    }
  }
  __shared__ float4 pr[4][48];
  pr[sub][cg] = acc;
  __syncthreads();
  if (sub == 0){
    #pragma unroll
    for (int s=1; s<4; s++){
      float4 xv = pr[s][cg];
      if (avg){ acc.x+=xv.x; acc.y+=xv.y; acc.z+=xv.z; acc.w+=xv.w; }
      else { acc.x=fmaxf(acc.x,xv.x); acc.y=fmaxf(acc.y,xv.y);
             acc.z=fmaxf(acc.z,xv.z); acc.w=fmaxf(acc.w,xv.w); }
    }
    if (avg){ acc.x*=(1.f/128.f); acc.y*=(1.f/128.f); acc.z*=(1.f/128.f); acc.w*=(1.f/128.f); }
    unsigned int lo = (unsigned int)f2bf(acc.x*SCALE) | ((unsigned int)f2bf(acc.y*SCALE) << 16);
    unsigned int hi = (unsigned int)f2bf(acc.z*SCALE) | ((unsigned int)f2bf(acc.w*SCALE) << 16);
    uint2 st; st.x = lo; st.y = hi;
    *(uint2*)(poolq + ((size_t)b*128 + n)*192 + cg*4) = st;
  }
}

// ---------------- attention: one block per (window, batch, head) ----------------
// Wave wv owns 32 queries (m in [wv*32,+32)), all 128 tokens. Wave-local softmax;
// P->PV handoff in-register via k-permutation (Vt columns pre-permuted to match).
// rpb prefetched pre-barrier as 8 coalesced uint4 (hidden under K/V staging latency);
// mask loaded in-loop with EXACT values (numerics identical to round 1: absmax 0.03125).
// Epilogue: per-wave LDS transpose (overlay Kt/Vt after barrier 2) -> 64B-contiguous stores.
__global__ __launch_bounds__(256, 4)
void attn_kernel(const void* __restrict__ qkv,
                 const unsigned short* __restrict__ poolq,
                 const void* __restrict__ mask,
                 const unsigned short* __restrict__ rpbP,
                 void* __restrict__ out)
{
  const int isbf = detect_bf16(qkv);
  const int iw = blockIdx.x, b = blockIdx.y, head = blockIdx.z;
  const int hb = iw >> 3, wb = iw & 7;   // window: h in [hb*8,+8), w in [wb*16,+16)
  const int qb = iw & 7;                 // torch .repeat quirk: pooled-q batch = iw % 8
  const int tid = threadIdx.x;
  const int lane = tid & 63, wv = tid >> 6;
  const int quad = lane >> 4, c16 = lane & 15;

  __shared__ __align__(16) unsigned char lds_raw[18944];
  unsigned short (*Kt)[40]  = (unsigned short (*)[40])lds_raw;            // 10240 B
  unsigned short (*Vt)[136] = (unsigned short (*)[136])(lds_raw + 10240); // 8704 B

  // ---- prefetch Q frags + rpb tiles (independent of LDS; hide under staging) ----
  short8 qf[2];
  #pragma unroll
  for (int tm=0; tm<2; tm++)
    qf[tm] = *(const short8*)(poolq + ((size_t)(qb*128 + (wv*2+tm)*16 + c16))*192 + head*32 + quad*8);
  uint4 rfr[8];
  {
    const unsigned short* rb = rpbP + (size_t)head*16384;
    #pragma unroll
    for (int tn=0; tn<8; tn++)
      rfr[tn] = *(const uint4*)(rb + (size_t)((tn*4 + wv)*64 + lane)*8);
  }

  // ---- stage Kt and Vt (cooperative; each thread one half-row of one token) ----
  {
    const int tok = tid >> 1;            // token 0..127
    const int dh  = (tid & 1) << 4;      // dim half 0 / 16
    const size_t rowidx = ((size_t)((b*128 + hb*8 + (tok>>4))*128 + wb*16 + (tok&15)))*192 + head*32 + dh;
    short8 k0 = ld8(qkv, KOFF + rowidx, isbf);
    short8 k1 = ld8(qkv, KOFF + rowidx + 8, isbf);
    *(short8*)(&Kt[tok][dh])     = k0;
    *(short8*)(&Kt[tok][dh + 8]) = k1;
    short8 v0 = ld8(qkv, VOFF + rowidx, isbf);
    short8 v1 = ld8(qkv, VOFF + rowidx + 8, isbf);
    // permuted column: within each 32-token block, n = b16*16+q*4+r -> pos = q*8+b16*4+r
    const int t5 = tok & 31;
    const int stok = (tok & ~31) | (((t5>>2)&3)*8) | (((t5>>4)&1)*4) | (t5&3);
    #pragma unroll
    for (int u=0; u<8; u++){
      Vt[dh + u][stok]     = (unsigned short)v0[u];
      Vt[dh + 8 + u][stok] = (unsigned short)v1[u];
    }
  }

  __syncthreads();   // BARRIER 1: Kt/Vt visible to all waves

  // ---- S^T tiles + bias: D[i = token n (quad*4+r in tile tn)][j = query m (c16)] ----
  f32x4 acc[8][2];
  const size_t mbase = (size_t)iw*16384;
  #pragma unroll
  for (int tn=0; tn<8; tn++){
    short8 kA = *(const short8*)(&Kt[tn*16 + c16][quad*8]);
    f32x4 z = {0.f, 0.f, 0.f, 0.f};
    acc[tn][0] = __builtin_amdgcn_mfma_f32_16x16x32_bf16(kA, qf[0], z, 0, 0, 0);
    acc[tn][1] = __builtin_amdgcn_mfma_f32_16x16x32_bf16(kA, qf[1], z, 0, 0, 0);
    const int nb = tn*16 + quad*4;
    const uint4 rv = rfr[tn];
    {
      const int m = wv*32 + c16;         // tm = 0
      float4 mv = ld4(mask, mbase + (size_t)m*128 + nb, isbf);
      acc[tn][0][0] += mv.x + bf2f((unsigned short)(rv.x & 0xffffu));
      acc[tn][0][1] += mv.y + bf2f((unsigned short)(rv.x >> 16));
      acc[tn][0][2] += mv.z + bf2f((unsigned short)(rv.y & 0xffffu));
      acc[tn][0][3] += mv.w + bf2f((unsigned short)(rv.y >> 16));
    }
    {
      const int m = wv*32 + 16 + c16;    // tm = 1
      float4 mv = ld4(mask, mbase + (size_t)m*128 + nb, isbf);
      acc[tn][1][0] += mv.x + bf2f((unsigned short)(rv.z & 0xffffu));
      acc[tn][1][1] += mv.y + bf2f((unsigned short)(rv.z >> 16));
      acc[tn][1][2] += mv.z + bf2f((unsigned short)(rv.w & 0xffffu));
      acc[tn][1][3] += mv.w + bf2f((unsigned short)(rv.w >> 16));
    }
  }

  // ---- wave-local softmax over tokens per query + in-register bf16 pack ----
  float wsc[2];
  short8 pa[4][2];
  #pragma unroll
  for (int tm=0; tm<2; tm++){
    float mx = acc[0][tm][0];
    #pragma unroll
    for (int tn=0; tn<8; tn++)
      #pragma unroll
      for (int r=0; r<4; r++) mx = fmaxf(mx, acc[tn][tm][r]);
    mx = fmaxf(mx, __shfl_xor(mx, 16));
    mx = fmaxf(mx, __shfl_xor(mx, 32));
    float s = 0.f;
    #pragma unroll
    for (int tn=0; tn<8; tn++)
      #pragma unroll
      for (int r=0; r<4; r++){
        float p = __expf(acc[tn][tm][r] - mx);
        acc[tn][tm][r] = p;
        s += p;
      }
    s += __shfl_xor(s, 16);
    s += __shfl_xor(s, 32);
    wsc[tm] = 1.0f / s;   // applied at epilogue (P stays unnormalized in [0,1])
    // pack PV B-frags: pa[jt][tm][u] = P[jt*32 + pi(quad*8+u)][m]  (all in-lane)
    #pragma unroll
    for (int jt=0; jt<4; jt++)
      #pragma unroll
      for (int u=0; u<8; u++)
        pa[jt][tm][u] = (short)(__float_as_uint(acc[2*jt + (u>>2)][tm][u & 3]) >> 16);
  }

  // ---- O^T = V^T · P : D[i = d][j = m], k-order permuted consistently via Vt columns ----
  f32x4 o[2][2];   // o[tm][dt]
  #pragma unroll
  for (int tm=0; tm<2; tm++)
    #pragma unroll
    for (int dt=0; dt<2; dt++){ f32x4 z = {0.f,0.f,0.f,0.f}; o[tm][dt] = z; }
  #pragma unroll
  for (int jt=0; jt<4; jt++){
    short8 vA0 = *(const short8*)&Vt[c16][jt*32 + quad*8];
    short8 vA1 = *(const short8*)&Vt[16 + c16][jt*32 + quad*8];
    o[0][0] = __builtin_amdgcn_mfma_f32_16x16x32_bf16(vA0, pa[jt][0], o[0][0], 0, 0, 0);
    o[0][1] = __builtin_amdgcn_mfma_f32_16x16x32_bf16(vA1, pa[jt][0], o[0][1], 0, 0, 0);
    o[1][0] = __builtin_amdgcn_mfma_f32_16x16x32_bf16(vA0, pa[jt][1], o[1][0], 0, 0, 0);
    o[1][1] = __builtin_amdgcn_mfma_f32_16x16x32_bf16(vA1, pa[jt][1], o[1][1], 0, 0, 0);
  }

  __syncthreads();   // BARRIER 2: all PV reads of Kt/Vt done -> LDS reusable as fp32 epilogue buf

  // ---- epilogue: per-wave LDS transpose -> 64B-contiguous stores per lane ----
  float* w = (float*)lds_raw + wv*1152;   // 32 tokens x 36 floats (4608 B/wave)
  #pragma unroll
  for (int tm=0; tm<2; tm++)
    #pragma unroll
    for (int dt=0; dt<2; dt++)
      #pragma unroll
      for (int r=0; r<4; r++)
        w[(tm*16 + c16)*36 + dt*16 + quad*4 + r] = o[tm][dt][r] * wsc[tm];
  // wave-private region; in-wave DS ordering suffices
  {
    const int tk = lane >> 1;            // local output token (query) 0..31
    const int h2 = lane & 1;             // dim half
    const int token = wv*32 + tk;
    const int hh = hb*8 + (token >> 4), ww = wb*16 + (token & 15);
    const size_t obase = ((size_t)((b*128 + hh)*128 + ww))*192 + head*32 + h2*16;
    #pragma unroll
    for (int it=0; it<4; it++){
      float4 val = *(const float4*)&w[tk*36 + h2*16 + it*4];
      if (isbf){
        unsigned int lo = (unsigned int)f2bf(val.x) | ((unsigned int)f2bf(val.y) << 16);
        unsigned int hi = (unsigned int)f2bf(val.z) | ((unsigned int)f2bf(val.w) << 16);
        uint2 st; st.x = lo; st.y = hi;
        *(uint2*)((unsigned short*)out + obase + it*4) = st;
      } else {
        *(float4*)((float*)out + obase + it*4) = val;
      }
    }
  }
}

extern "C" void kernel_launch(void* const* d_in, const int* in_sizes, int n_in,
                              void* d_out, int out_size, void* d_ws, size_t ws_size,
                              hipStream_t stream)
{
  const void* qkv  = d_in[0];
  const void* mask = d_in[1];
  const int* rel_idx = (const int*)d_in[17];

  // Workspace layout (NOTE: poolq is 8*128*192*2 = 393216 B — rounds 2/3 under-sized
  // it at 196608 and pool_kernel clobbered the bias table placed after it; poolq LAST):
  float* pos_table      = (float*)d_ws;                                   // [0, 12288)
  unsigned short* rpbP  = (unsigned short*)((char*)d_ws + 12288);         // [12288, 208896)
  unsigned short* poolq = (unsigned short*)((char*)d_ws + 208896);        // [208896, 602112)

  posmlp_kernel<<<1, 512, 0, stream>>>(qkv, d_in[16],
      d_in[2], d_in[3], d_in[4], d_in[5], d_in[6], d_in[7],
      d_in[8], d_in[9], d_in[10], d_in[11], d_in[12], d_in[13],
      d_in[14], d_in[15], pos_table);
  gatherP_kernel<<<96, 256, 0, stream>>>(rel_idx, pos_table, rpbP);
  pool_kernel<<<dim3(128, 8), 192, 0, stream>>>(qkv, poolq);
  attn_kernel<<<dim3(128, 8, 6), 256, 0, stream>>>(qkv, poolq, mask, rpbP, d_out);
}

// Round 5
// 635.909 us; speedup vs baseline: 1.2936x; 1.2205x over previous
//
#include <hip/hip_runtime.h>
#include <cstdint>
#include <cstddef>

typedef __attribute__((ext_vector_type(8))) short short8;
typedef __attribute__((ext_vector_type(4))) float f32x4;

#define SCALE 0.17677669529663687f
#define KOFF 25165824UL
#define VOFF 50331648UL

__device__ __forceinline__ float bf2f(unsigned short u){
  union { unsigned int i; float f; } x; x.i = ((unsigned int)u) << 16; return x.f;
}
__device__ __forceinline__ unsigned short f2bf(float f){
  union { float f; unsigned int i; } x; x.f = f;
  unsigned int u = x.i;
  unsigned int r = u + 0x7fffu + ((u >> 16) & 1u);
  return (unsigned short)(r >> 16);
}

// Detect whether external float tensors are stored as bf16 (1) or fp32 (0).
__device__ __forceinline__ int detect_bf16(const void* probe){
  const unsigned short* p = (const unsigned short*)probe;
  int ok = 1;
  #pragma unroll
  for (int i = 0; i < 32; i++){
    unsigned short u = p[2*i];
    int e = (u >> 7) & 0xFF;
    ok &= (e >= 0x60 && e <= 0x90) ? 1 : 0;
  }
  return ok;
}

__device__ __forceinline__ float ld1(const void* p, size_t i, int isbf){
  return isbf ? bf2f(((const unsigned short*)p)[i]) : ((const float*)p)[i];
}
// 8 consecutive elements (i % 8 == 0) -> bf16 frag (RTE conversion on fp32 path)
__device__ __forceinline__ short8 ld8(const void* p, size_t i, int isbf){
  short8 r;
  if (isbf){
    r = *(const short8*)((const unsigned short*)p + i);
  } else {
    const float4* f = (const float4*)((const float*)p + i);
    float4 u0 = f[0], u1 = f[1];
    r[0] = (short)f2bf(u0.x); r[1] = (short)f2bf(u0.y);
    r[2] = (short)f2bf(u0.z); r[3] = (short)f2bf(u0.w);
    r[4] = (short)f2bf(u1.x); r[5] = (short)f2bf(u1.y);
    r[6] = (short)f2bf(u1.z); r[7] = (short)f2bf(u1.w);
  }
  return r;
}
// 4 consecutive elements (i % 4 == 0) -> float4
__device__ __forceinline__ float4 ld4(const void* p, size_t i, int isbf){
  if (!isbf) return *(const float4*)((const float*)p + i);
  const unsigned short* u = (const unsigned short*)p + i;
  uint2 w = *(const uint2*)u;
  float4 r;
  r.x = bf2f((unsigned short)(w.x & 0xffffu)); r.y = bf2f((unsigned short)(w.x >> 16));
  r.z = bf2f((unsigned short)(w.y & 0xffffu)); r.w = bf2f((unsigned short)(w.y >> 16));
  return r;
}

// ---------------- DynamicPosBias MLP: [465,2] -> [465,6] (fp32 out) ----------------
// Parallelized: 2 blocks x 256 threads; all 498 params staged to LDS once per block.
// Per-row arithmetic is bit-identical to the previous (passing) single-block version.
__global__ void posmlp_kernel(const void* __restrict__ probe,
    const void* __restrict__ rpe,
    const void* __restrict__ w0, const void* __restrict__ b0,
    const void* __restrict__ g1, const void* __restrict__ be1,
    const void* __restrict__ w1, const void* __restrict__ bb1,
    const void* __restrict__ g2, const void* __restrict__ be2,
    const void* __restrict__ w2, const void* __restrict__ bb2,
    const void* __restrict__ g3, const void* __restrict__ be3,
    const void* __restrict__ w3, const void* __restrict__ bb3,
    float* __restrict__ pos_table)
{
  const int isbf = detect_bf16(probe);
  __shared__ float W0[24], B0[12], G1[12], BE1[12], W1[144], BB1[12];
  __shared__ float G2[12], BE2[12], W2[144], BB2[12];
  __shared__ float G3[12], BE3[12], W3[72], BB3[6];
  {
    const int t = threadIdx.x, nt = blockDim.x;
    for (int i=t;i<24;i+=nt)  W0[i]  = ld1(w0,i,isbf);
    for (int i=t;i<12;i+=nt)  B0[i]  = ld1(b0,i,isbf);
    for (int i=t;i<12;i+=nt)  G1[i]  = ld1(g1,i,isbf);
    for (int i=t;i<12;i+=nt)  BE1[i] = ld1(be1,i,isbf);
    for (int i=t;i<144;i+=nt) W1[i]  = ld1(w1,i,isbf);
    for (int i=t;i<12;i+=nt)  BB1[i] = ld1(bb1,i,isbf);
    for (int i=t;i<12;i+=nt)  G2[i]  = ld1(g2,i,isbf);
    for (int i=t;i<12;i+=nt)  BE2[i] = ld1(be2,i,isbf);
    for (int i=t;i<144;i+=nt) W2[i]  = ld1(w2,i,isbf);
    for (int i=t;i<12;i+=nt)  BB2[i] = ld1(bb2,i,isbf);
    for (int i=t;i<12;i+=nt)  G3[i]  = ld1(g3,i,isbf);
    for (int i=t;i<12;i+=nt)  BE3[i] = ld1(be3,i,isbf);
    for (int i=t;i<72;i+=nt)  W3[i]  = ld1(w3,i,isbf);
    for (int i=t;i<6;i+=nt)   BB3[i] = ld1(bb3,i,isbf);
  }
  __syncthreads();
  const int r = blockIdx.x * blockDim.x + threadIdx.x;
  if (r >= 465) return;
  float x0 = ld1(rpe, 2*r, isbf), x1 = ld1(rpe, 2*r+1, isbf);
  float h[12], y[12];
  #pragma unroll
  for (int j=0;j<12;j++) h[j] = x0*W0[j] + x1*W0[12+j] + B0[j];

  {
    float m=0.f;
    #pragma unroll
    for (int j=0;j<12;j++) m += h[j];
    m *= (1.f/12.f);
    float v=0.f;
    #pragma unroll
    for (int j=0;j<12;j++){ float d=h[j]-m; v += d*d; }
    v *= (1.f/12.f);
    float rs = 1.0f/sqrtf(v + 1e-5f);
    #pragma unroll
    for (int j=0;j<12;j++) y[j] = fmaxf((h[j]-m)*rs*G1[j] + BE1[j], 0.f);
    #pragma unroll
    for (int j=0;j<12;j++){
      float s = BB1[j];
      #pragma unroll
      for (int i=0;i<12;i++) s += y[i]*W1[i*12+j];
      h[j] = s;
    }
  }
  {
    float m=0.f;
    #pragma unroll
    for (int j=0;j<12;j++) m += h[j];
    m *= (1.f/12.f);
    float v=0.f;
    #pragma unroll
    for (int j=0;j<12;j++){ float d=h[j]-m; v += d*d; }
    v *= (1.f/12.f);
    float rs = 1.0f/sqrtf(v + 1e-5f);
    #pragma unroll
    for (int j=0;j<12;j++) y[j] = fmaxf((h[j]-m)*rs*G2[j] + BE2[j], 0.f);
    #pragma unroll
    for (int j=0;j<12;j++){
      float s = BB2[j];
      #pragma unroll
      for (int i=0;i<12;i++) s += y[i]*W2[i*12+j];
      h[j] = s;
    }
  }
  {
    float m=0.f;
    #pragma unroll
    for (int j=0;j<12;j++) m += h[j];
    m *= (1.f/12.f);
    float v=0.f;
    #pragma unroll
    for (int j=0;j<12;j++){ float d=h[j]-m; v += d*d; }
    v *= (1.f/12.f);
    float rs = 1.0f/sqrtf(v + 1e-5f);
    #pragma unroll
    for (int j=0;j<12;j++) y[j] = fmaxf((h[j]-m)*rs*G3[j] + BE3[j], 0.f);
    #pragma unroll
    for (int o=0;o<6;o++){
      float s = BB3[o];
      #pragma unroll
      for (int i=0;i<12;i++) s += y[i]*W3[i*6+o];
      pos_table[r*6+o] = s;
    }
  }
}

// ---------------- permuted rpb gather: rpbP[h][tn][wv][lane][tm][r] (bf16) ----------------
// value = f2bf(pos_table[rel_idx[m*128+n]*6 + h])  (same rounding as round-1 gatherN)
//   m = wv*32 + tm*16 + (lane&15), n = tn*16 + (lane>>4)*4 + r
// attn's lane then reads ONE uint4 per tn: {tm0 r0..3, tm1 r0..3}, fully coalesced.
__global__ void gatherP_kernel(const int* __restrict__ rel_idx,
                               const float* __restrict__ pos_table,
                               unsigned short* __restrict__ rpbP)
{
  const int t = blockIdx.x * 256 + threadIdx.x;   // 24576 total
  const int tm = t & 1, lane = (t >> 1) & 63, wv = (t >> 7) & 3, tn = (t >> 9) & 7, h = t >> 12;
  const int c16 = lane & 15, quad = lane >> 4;
  const int m = wv*32 + tm*16 + c16;
  const int nb = tn*16 + quad*4;
  const int* ri = rel_idx + m*128 + nb;
  unsigned int lo = (unsigned int)f2bf(pos_table[ri[0]*6 + h])
                  | ((unsigned int)f2bf(pos_table[ri[1]*6 + h]) << 16);
  unsigned int hi = (unsigned int)f2bf(pos_table[ri[2]*6 + h])
                  | ((unsigned int)f2bf(pos_table[ri[3]*6 + h]) << 16);
  uint2 st; st.x = lo; st.y = hi;
  *(uint2*)(rpbP + ((size_t)((h*8 + tn)*4 + wv)*64 + lane)*8 + tm*4) = st;
}

// ---------------- pooled query: avg (c<96) / max (c>=96), *scale, bf16 out ----------------
__global__ void pool_kernel(const void* __restrict__ qkv,
                            unsigned short* __restrict__ poolq)
{
  const int isbf = detect_bf16(qkv);
  const int b = blockIdx.y;
  const int n = blockIdx.x;            // n = ph*16 + pw
  const int t = threadIdx.x;           // 0..191
  const int cg = t % 48, sub = t / 48; // 48 float4 channel groups, 4 token subsets
  const int ph = n >> 4, pw = n & 15;
  const size_t cell = ((size_t)(b*16384 + ph*16*128 + pw*8))*192 + cg*4;
  const bool avg = (cg < 24);
  float4 acc;
  if (avg){ acc.x=0.f; acc.y=0.f; acc.z=0.f; acc.w=0.f; }
  else    { acc.x=-3.4e38f; acc.y=-3.4e38f; acc.z=-3.4e38f; acc.w=-3.4e38f; }
  #pragma unroll
  for (int hh=0; hh<4; hh++){
    const int hi = sub*4 + hh;
    #pragma unroll
    for (int wi=0; wi<8; wi++){
      float4 xv = ld4(qkv, cell + (size_t)(hi*128 + wi)*192, isbf);
      if (avg){ acc.x+=xv.x; acc.y+=xv.y; acc.z+=xv.z; acc.w+=xv.w; }
      else { acc.x=fmaxf(acc.x,xv.x); acc.y=fmaxf(acc.y,xv.y);
             acc.z=fmaxf(acc.z,xv.z); acc.w=fmaxf(acc.w,xv.w); }
    }
  }
  __shared__ float4 pr[4][48];
  pr[sub][cg] = acc;
  __syncthreads();
  if (sub == 0){
    #pragma unroll
    for (int s=1; s<4; s++){
      float4 xv = pr[s][cg];
      if (avg){ acc.x+=xv.x; acc.y+=xv.y; acc.z+=xv.z; acc.w+=xv.w; }
      else { acc.x=fmaxf(acc.x,xv.x); acc.y=fmaxf(acc.y,xv.y);
             acc.z=fmaxf(acc.z,xv.z); acc.w=fmaxf(acc.w,xv.w); }
    }
    if (avg){ acc.x*=(1.f/128.f); acc.y*=(1.f/128.f); acc.z*=(1.f/128.f); acc.w*=(1.f/128.f); }
    unsigned int lo = (unsigned int)f2bf(acc.x*SCALE) | ((unsigned int)f2bf(acc.y*SCALE) << 16);
    unsigned int hi = (unsigned int)f2bf(acc.z*SCALE) | ((unsigned int)f2bf(acc.w*SCALE) << 16);
    uint2 st; st.x = lo; st.y = hi;
    *(uint2*)(poolq + ((size_t)b*128 + n)*192 + cg*4) = st;
  }
}

// ---------------- attention: one block per (window, batch, head) ----------------
// Wave wv owns 32 queries (m in [wv*32,+32)), all 128 tokens. Wave-local softmax;
// P->PV handoff in-register via k-permutation (Vt columns pre-permuted to match).
// rpb prefetched pre-barrier as 8 coalesced uint4; mask loaded in-loop EXACT.
// Grid: 1-D 6144 with XCD-chunked swizzle; decoded order head-fastest, then b, then iw:
//   6 consecutive blocks share a K/V slice; 48 share a mask window -> L2-resident per XCD.
// Epilogue: per-wave LDS transpose -> each lane stores one full 64B line.
__global__ __launch_bounds__(256, 4)
void attn_kernel(const void* __restrict__ qkv,
                 const unsigned short* __restrict__ poolq,
                 const void* __restrict__ mask,
                 const unsigned short* __restrict__ rpbP,
                 void* __restrict__ out)
{
  const int isbf = detect_bf16(qkv);
  // XCD-chunked bijective swizzle (6144 = 8 XCDs x 768)
  const int orig = blockIdx.x;
  const int lin  = (orig & 7) * 768 + (orig >> 3);
  const int head = lin % 6;
  const int rest = lin / 6;
  const int b    = rest & 7;
  const int iw   = rest >> 3;
  const int hb = iw >> 3, wb = iw & 7;   // window: h in [hb*8,+8), w in [wb*16,+16)
  const int qb = iw & 7;                 // torch .repeat quirk: pooled-q batch = iw % 8
  const int tid = threadIdx.x;
  const int lane = tid & 63, wv = tid >> 6;
  const int quad = lane >> 4, c16 = lane & 15;

  __shared__ __align__(16) unsigned char lds_raw[18944];
  unsigned short (*Kt)[40]  = (unsigned short (*)[40])lds_raw;            // 10240 B
  unsigned short (*Vt)[136] = (unsigned short (*)[136])(lds_raw + 10240); // 8704 B

  // ---- prefetch Q frags + rpb tiles (independent of LDS; hide under staging) ----
  short8 qf[2];
  #pragma unroll
  for (int tm=0; tm<2; tm++)
    qf[tm] = *(const short8*)(poolq + ((size_t)(qb*128 + (wv*2+tm)*16 + c16))*192 + head*32 + quad*8);
  uint4 rfr[8];
  {
    const unsigned short* rb = rpbP + (size_t)head*16384;
    #pragma unroll
    for (int tn=0; tn<8; tn++)
      rfr[tn] = *(const uint4*)(rb + (size_t)((tn*4 + wv)*64 + lane)*8);
  }

  // ---- stage Kt and Vt (cooperative; each thread one half-row of one token) ----
  {
    const int tok = tid >> 1;            // token 0..127
    const int dh  = (tid & 1) << 4;      // dim half 0 / 16
    const size_t rowidx = ((size_t)((b*128 + hb*8 + (tok>>4))*128 + wb*16 + (tok&15)))*192 + head*32 + dh;
    short8 k0 = ld8(qkv, KOFF + rowidx, isbf);
    short8 k1 = ld8(qkv, KOFF + rowidx + 8, isbf);
    *(short8*)(&Kt[tok][dh])     = k0;
    *(short8*)(&Kt[tok][dh + 8]) = k1;
    short8 v0 = ld8(qkv, VOFF + rowidx, isbf);
    short8 v1 = ld8(qkv, VOFF + rowidx + 8, isbf);
    // permuted column: within each 32-token block, n = b16*16+q*4+r -> pos = q*8+b16*4+r
    const int t5 = tok & 31;
    const int stok = (tok & ~31) | (((t5>>2)&3)*8) | (((t5>>4)&1)*4) | (t5&3);
    #pragma unroll
    for (int u=0; u<8; u++){
      Vt[dh + u][stok]     = (unsigned short)v0[u];
      Vt[dh + 8 + u][stok] = (unsigned short)v1[u];
    }
  }

  __syncthreads();   // BARRIER 1: Kt/Vt visible to all waves

  // ---- S^T tiles + bias: D[i = token n (quad*4+r in tile tn)][j = query m (c16)] ----
  f32x4 acc[8][2];
  const size_t mbase = (size_t)iw*16384;
  #pragma unroll
  for (int tn=0; tn<8; tn++){
    short8 kA = *(const short8*)(&Kt[tn*16 + c16][quad*8]);
    f32x4 z = {0.f, 0.f, 0.f, 0.f};
    acc[tn][0] = __builtin_amdgcn_mfma_f32_16x16x32_bf16(kA, qf[0], z, 0, 0, 0);
    acc[tn][1] = __builtin_amdgcn_mfma_f32_16x16x32_bf16(kA, qf[1], z, 0, 0, 0);
    const int nb = tn*16 + quad*4;
    const uint4 rv = rfr[tn];
    {
      const int m = wv*32 + c16;         // tm = 0
      float4 mv = ld4(mask, mbase + (size_t)m*128 + nb, isbf);
      acc[tn][0][0] += mv.x + bf2f((unsigned short)(rv.x & 0xffffu));
      acc[tn][0][1] += mv.y + bf2f((unsigned short)(rv.x >> 16));
      acc[tn][0][2] += mv.z + bf2f((unsigned short)(rv.y & 0xffffu));
      acc[tn][0][3] += mv.w + bf2f((unsigned short)(rv.y >> 16));
    }
    {
      const int m = wv*32 + 16 + c16;    // tm = 1
      float4 mv = ld4(mask, mbase + (size_t)m*128 + nb, isbf);
      acc[tn][1][0] += mv.x + bf2f((unsigned short)(rv.z & 0xffffu));
      acc[tn][1][1] += mv.y + bf2f((unsigned short)(rv.z >> 16));
      acc[tn][1][2] += mv.z + bf2f((unsigned short)(rv.w & 0xffffu));
      acc[tn][1][3] += mv.w + bf2f((unsigned short)(rv.w >> 16));
    }
  }

  // ---- wave-local softmax over tokens per query + in-register bf16 pack ----
  float wsc[2];
  short8 pa[4][2];
  #pragma unroll
  for (int tm=0; tm<2; tm++){
    float mx = acc[0][tm][0];
    #pragma unroll
    for (int tn=0; tn<8; tn++)
      #pragma unroll
      for (int r=0; r<4; r++) mx = fmaxf(mx, acc[tn][tm][r]);
    mx = fmaxf(mx, __shfl_xor(mx, 16));
    mx = fmaxf(mx, __shfl_xor(mx, 32));
    float s = 0.f;
    #pragma unroll
    for (int tn=0; tn<8; tn++)
      #pragma unroll
      for (int r=0; r<4; r++){
        float p = __expf(acc[tn][tm][r] - mx);
        acc[tn][tm][r] = p;
        s += p;
      }
    s += __shfl_xor(s, 16);
    s += __shfl_xor(s, 32);
    wsc[tm] = 1.0f / s;   // applied at epilogue (P stays unnormalized in [0,1])
    // pack PV B-frags: pa[jt][tm][u] = P[jt*32 + pi(quad*8+u)][m]  (all in-lane)
    #pragma unroll
    for (int jt=0; jt<4; jt++)
      #pragma unroll
      for (int u=0; u<8; u++)
        pa[jt][tm][u] = (short)(__float_as_uint(acc[2*jt + (u>>2)][tm][u & 3]) >> 16);
  }

  // ---- O^T = V^T · P : D[i = d][j = m], k-order permuted consistently via Vt columns ----
  f32x4 o[2][2];   // o[tm][dt]
  #pragma unroll
  for (int tm=0; tm<2; tm++)
    #pragma unroll
    for (int dt=0; dt<2; dt++){ f32x4 z = {0.f,0.f,0.f,0.f}; o[tm][dt] = z; }
  #pragma unroll
  for (int jt=0; jt<4; jt++){
    short8 vA0 = *(const short8*)&Vt[c16][jt*32 + quad*8];
    short8 vA1 = *(const short8*)&Vt[16 + c16][jt*32 + quad*8];
    o[0][0] = __builtin_amdgcn_mfma_f32_16x16x32_bf16(vA0, pa[jt][0], o[0][0], 0, 0, 0);
    o[0][1] = __builtin_amdgcn_mfma_f32_16x16x32_bf16(vA1, pa[jt][0], o[0][1], 0, 0, 0);
    o[1][0] = __builtin_amdgcn_mfma_f32_16x16x32_bf16(vA0, pa[jt][1], o[1][0], 0, 0, 0);
    o[1][1] = __builtin_amdgcn_mfma_f32_16x16x32_bf16(vA1, pa[jt][1], o[1][1], 0, 0, 0);
  }

  __syncthreads();   // BARRIER 2: all PV reads of Kt/Vt done -> LDS reusable as fp32 epilogue buf

  // ---- epilogue: per-wave LDS transpose -> 64B-contiguous stores per lane ----
  float* w = (float*)lds_raw + wv*1152;   // 32 tokens x 36 floats (4608 B/wave)
  #pragma unroll
  for (int tm=0; tm<2; tm++)
    #pragma unroll
    for (int dt=0; dt<2; dt++)
      #pragma unroll
      for (int r=0; r<4; r++)
        w[(tm*16 + c16)*36 + dt*16 + quad*4 + r] = o[tm][dt][r] * wsc[tm];
  // wave-private region; in-wave DS ordering suffices
  {
    const int tk = lane >> 1;            // local output token (query) 0..31
    const int h2 = lane & 1;             // dim half
    const int token = wv*32 + tk;
    const int hh = hb*8 + (token >> 4), ww = wb*16 + (token & 15);
    const size_t obase = ((size_t)((b*128 + hh)*128 + ww))*192 + head*32 + h2*16;
    #pragma unroll
    for (int it=0; it<4; it++){
      float4 val = *(const float4*)&w[tk*36 + h2*16 + it*4];
      if (isbf){
        unsigned int lo = (unsigned int)f2bf(val.x) | ((unsigned int)f2bf(val.y) << 16);
        unsigned int hi = (unsigned int)f2bf(val.z) | ((unsigned int)f2bf(val.w) << 16);
        uint2 st; st.x = lo; st.y = hi;
        *(uint2*)((unsigned short*)out + obase + it*4) = st;
      } else {
        *(float4*)((float*)out + obase + it*4) = val;
      }
    }
  }
}

extern "C" void kernel_launch(void* const* d_in, const int* in_sizes, int n_in,
                              void* d_out, int out_size, void* d_ws, size_t ws_size,
                              hipStream_t stream)
{
  const void* qkv  = d_in[0];
  const void* mask = d_in[1];
  const int* rel_idx = (const int*)d_in[17];

  // Workspace layout (poolq is 8*128*192*2 = 393216 B; it goes LAST):
  float* pos_table      = (float*)d_ws;                                   // [0, 12288)
  unsigned short* rpbP  = (unsigned short*)((char*)d_ws + 12288);         // [12288, 208896)
  unsigned short* poolq = (unsigned short*)((char*)d_ws + 208896);        // [208896, 602112)

  posmlp_kernel<<<2, 256, 0, stream>>>(qkv, d_in[16],
      d_in[2], d_in[3], d_in[4], d_in[5], d_in[6], d_in[7],
      d_in[8], d_in[9], d_in[10], d_in[11], d_in[12], d_in[13],
      d_in[14], d_in[15], pos_table);
  gatherP_kernel<<<96, 256, 0, stream>>>(rel_idx, pos_table, rpbP);
  pool_kernel<<<dim3(128, 8), 192, 0, stream>>>(qkv, poolq);
  attn_kernel<<<6144, 256, 0, stream>>>(qkv, poolq, mask, rpbP, d_out);
}